// Round 7
// baseline (348.361 us; speedup 1.0000x reference)
//
#include <hip/hip_runtime.h>

typedef unsigned int uint;
typedef unsigned short ushort;

typedef float f32x4 __attribute__((ext_vector_type(4)));
typedef __bf16 bf16x8 __attribute__((ext_vector_type(8)));

__device__ __forceinline__ float bf2f(uint bits) {
  return __uint_as_float(bits << 16);
}
__device__ __forceinline__ ushort f2bf(float f) {
  uint u = __float_as_uint(f);
  u += 0x7fffu + ((u >> 16) & 1u);   // round-to-nearest-even
  return (ushort)(u >> 16);
}
__device__ __forceinline__ uint pack2(float a, float b) {
  return (uint)f2bf(a) | ((uint)f2bf(b) << 16);
}

// inclusive block scan of per-thread values over 256 threads (ts = 256-slot LDS)
__device__ __forceinline__ void block_scan256(int v, int* ts, int tid) {
  ts[tid] = v;
  __syncthreads();
  for (int off = 1; off < 256; off <<= 1) {
    int t_ = 0;
    if (tid >= off) t_ = ts[tid - off];
    __syncthreads();
    if (tid >= off) ts[tid] += t_;
    __syncthreads();
  }
}

// ================= one-pass bucket scatter (single edge read) ================
// Coarse bucket = 512-node range (B = ceil(n/512); B <= 256 for n <= 131072).
// Each block stages 4096 edges in LDS, histograms them, RESERVES a per-bucket
// range via one global atomicAdd per (block,bucket) into capacity-padded
// bucket regions (cap = 2x mean; overflow prob for uniform edges ~ e^-2700),
// then scatters from LDS. Bucket order is arbitrary -> fine_k's counting sort
// and the sum-aggregation are order-independent.
// Blocks [P, P+16) piggyback the W pre-swizzle + dtype probe (saves a launch).
__global__ __launch_bounds__(256) void ecat_k(
    const int* __restrict__ src, const int* __restrict__ dst,
    uint* __restrict__ ebuf_d, ushort* __restrict__ ebuf_s,
    int* __restrict__ gcur_d, int* __restrict__ gcur_s,
    int B, int cap, int E, int P,
    const void* __restrict__ W1p, const void* __restrict__ W2p,
    ushort* __restrict__ wf1, ushort* __restrict__ wf2,
    const uint* __restrict__ xu, int* __restrict__ flagp) {
  __shared__ int s_s[4096], s_d[4096];   // 32 KB edge stage
  __shared__ int hd[1024], hs[1024];     // 8 KB hist -> cursors
  __shared__ int bfs;
  const int tid = threadIdx.x;

  if (blockIdx.x >= P) {   // ---- wswz role (16 blocks) ----
    if (tid < 64) {        // wave 0: bf16-vs-f32 probe on first 64 feat words
      uint u = xu[tid];
      uint e = (u >> 7) & 0xFFu;
      unsigned long long mm = __ballot(e >= 116u && e <= 130u);
      if (tid == 0) {
        int f = (__builtin_popcountll(mm) >= 32) ? 1 : 0;
        bfs = f;
        if (blockIdx.x == P) flagp[0] = f;
      }
    }
    __syncthreads();
    const int bf = bfs;
    int vid = (blockIdx.x - P) * 256 + tid;   // 0..4095
    const void* W = (vid & 2048) ? W2p : W1p;
    ushort* wf = (vid & 2048) ? wf2 : wf1;
    int chunk = vid & 2047;
    int n0 = chunk & 15;
    int quad = (chunk >> 4) & 3;
    int kk = (chunk >> 6) & 3;
    int c = chunk >> 8;
    int col = c * 16 + n0;
#pragma unroll
    for (int j = 0; j < 8; ++j) {
      int idx = (kk * 32 + quad * 8 + j) * 128 + col;
      ushort v = bf ? ((const ushort*)W)[idx] : f2bf(((const float*)W)[idx]);
      wf[chunk * 8 + j] = v;
    }
    return;
  }

  // ---- edge-scatter role ----
  const int blk = blockIdx.x;
  for (int i = tid; i < B; i += 256) { hd[i] = 0; hs[i] = 0; }
  int e0 = blk << 12;
  int cnt = E - e0;
  if (cnt > 4096) cnt = 4096;
  __syncthreads();
  for (int j = tid; j < cnt; j += 256) {
    int s = src[e0 + j], d = dst[e0 + j];
    s_s[j] = s;
    s_d[j] = d;
    atomicAdd(&hd[d >> 9], 1);
    atomicAdd(&hs[s >> 9], 1);
  }
  __syncthreads();
  for (int i = tid; i < B; i += 256) {   // reserve ranges (global atomics)
    int c = hd[i];
    if (c) hd[i] = i * cap + atomicAdd(&gcur_d[i], c);
    int c2 = hs[i];
    if (c2) hs[i] = i * cap + atomicAdd(&gcur_s[i], c2);
  }
  __syncthreads();
  for (int j = tid; j < cnt; j += 256) {
    int s = s_s[j], d = s_d[j];
    int pd = atomicAdd(&hd[d >> 9], 1);
    ebuf_d[pd] = (uint)s | ((uint)(d & 511) << 17);   // src(17b)|dstlocal(9b)
    int ps = atomicAdd(&hs[s >> 9], 1);
    ebuf_s[ps] = (ushort)(s & 511);
  }
}

// K5: per-bucket fine pass (+ fused layer-1 GEMM on the src side).
// Dense base recovered by an in-block reduce over the final global cursor
// counts. dst side: 512-bin LDS histogram + scan -> row_off/nd/csr.
// src side: histogram -> ns, then this block ALREADY holds the out-degree
// counts for its 512 rows in LDS -> do the 512-row layer-1 GEMM here
// (8 passes of the 64-row pattern). Saves one dispatch + the ns round-trip;
// GEMM work overlaps the dst-side sort blocks on other CUs.
__global__ __launch_bounds__(256) void fine_k(
    const uint* __restrict__ ebuf_d, const ushort* __restrict__ ebuf_s,
    const int* __restrict__ gcur_d, const int* __restrict__ gcur_s,
    int* __restrict__ row_off, int* __restrict__ csr,
    float* __restrict__ ns, float* __restrict__ nd,
    const void* __restrict__ xp, const ushort* __restrict__ wf1,
    ushort* __restrict__ t, const int* __restrict__ flagp,
    int B, int cap, int n, int E) {
  __shared__ int cnt[512];
  __shared__ int off[512];
  __shared__ int ts[256];
  __shared__ __align__(16) ushort Ws[16384];
  const int tid = threadIdx.x;
  const int id = blockIdx.x;          // [0,2B)
  for (int i = tid; i < 512; i += 256) cnt[i] = 0;

  const int b = (id < B) ? id : id - B;
  const int* cur = (id < B) ? gcur_d : gcur_s;
  // dense base lo = sum_{i<b} cur[i]; bucket count cb = cur[b]
  int part = 0;
#pragma unroll
  for (int k = 0; k < 4; ++k) {
    int i = tid * 4 + k;
    if (i < b) part += cur[i];
  }
  block_scan256(part, ts, tid);   // barriers also publish the cnt[] zero-init
  int lo = ts[255];
  int cb = cur[b];
  const int rb = b * cap;          // padded read base
  __syncthreads();                 // ts reused below

  if (id < B) {
    for (int e = tid; e < cb; e += 256)
      atomicAdd(&cnt[(ebuf_d[rb + e] >> 17) & 511], 1);
    __syncthreads();
    int c0 = cnt[2 * tid], c1 = cnt[2 * tid + 1];
    block_scan256(c0 + c1, ts, tid);
    int excl = (tid > 0) ? ts[tid - 1] : 0;
    off[2 * tid] = excl;
    off[2 * tid + 1] = excl + c0;
    __syncthreads();
    for (int i = tid; i < 512; i += 256) {
      int g = b * 512 + i;
      if (g < n) {
        row_off[g] = lo + off[i];
        nd[g] = rsqrtf(fmaxf((float)cnt[i], 1.f));
      }
    }
    if (id == 0 && tid == 0) row_off[n] = E;
    __syncthreads();
    for (int i = tid; i < 512; i += 256) cnt[i] = off[i];  // cnt -> cursor
    __syncthreads();
    for (int e = tid; e < cb; e += 256) {
      uint v = ebuf_d[rb + e];
      int l = (v >> 17) & 511;
      int slot = atomicAdd(&cnt[l], 1);
      csr[lo + slot] = (int)(v & 0x1FFFFu);   // L2 write-combines to full lines
    }
  } else {
    // ---- src side: stage W1 fragments early (read after the hist barrier)
#pragma unroll
    for (int i = 0; i < 8; ++i)
      ((uint4*)Ws)[i * 256 + tid] = ((const uint4*)wf1)[i * 256 + tid];
    for (int e = tid; e < cb; e += 256)
      atomicAdd(&cnt[ebuf_s[rb + e]], 1);
    __syncthreads();
    for (int i = tid; i < 512; i += 256) {
      int g = b * 512 + i;
      if (g < n) ns[g] = rsqrtf(fmaxf((float)cnt[i], 1.f));
    }
    // ---- fused layer-1 GEMM for rows [b*512, b*512+512) ----
    const int eff_bf = *flagp;
    const int w = tid >> 6;
    const int lane = tid & 63;
    const int m = lane & 15;
    const int quad = lane >> 4;
    for (int pass = 0; pass < 8; ++pass) {
      const int rowbase = b * 512 + pass * 64;
      const int gr_a = rowbase + w * 16 + m;
      const int row_ld = (gr_a < n) ? gr_a : (n - 1);   // clamp: no OOB fault
      bf16x8 a[4];
      if (eff_bf) {
        const ushort* xr = (const ushort*)xp + (size_t)row_ld * 128 + quad * 8;
#pragma unroll
        for (int kk = 0; kk < 4; ++kk)
          a[kk] = *(const bf16x8*)(xr + kk * 32);
      } else {
        const float* xr = (const float*)xp + (size_t)row_ld * 128 + quad * 8;
#pragma unroll
        for (int kk = 0; kk < 4; ++kk) {
          float4 f0 = *(const float4*)(xr + kk * 32);
          float4 f1 = *(const float4*)(xr + kk * 32 + 4);
          uint4 v;
          v.x = pack2(f0.x, f0.y); v.y = pack2(f0.z, f0.w);
          v.z = pack2(f1.x, f1.y); v.w = pack2(f1.z, f1.w);
          a[kk] = __builtin_bit_cast(bf16x8, v);
        }
      }
      int grs[4];
      float nsv[4];
#pragma unroll
      for (int reg = 0; reg < 4; ++reg) {
        int li = pass * 64 + w * 16 + quad * 4 + reg;   // local row in bucket
        grs[reg] = b * 512 + li;
        nsv[reg] = rsqrtf(fmaxf((float)cnt[li], 1.f));  // == ns[row]
      }
#pragma unroll
      for (int c = 0; c < 8; ++c) {
        f32x4 acc = {0.f, 0.f, 0.f, 0.f};
#pragma unroll
        for (int kk = 0; kk < 4; ++kk) {
          bf16x8 bb = *(const bf16x8*)&Ws[(((c * 4 + kk) * 4 + quad) * 16 + m) * 8];
          acc = __builtin_amdgcn_mfma_f32_16x16x32_bf16(a[kk], bb, acc, 0, 0, 0);
        }
        int col = c * 16 + m;
#pragma unroll
        for (int reg = 0; reg < 4; ++reg) {
          if (grs[reg] < n)
            t[(size_t)grs[reg] * 128 + col] = f2bf(acc[reg] * nsv[reg]);
        }
      }
    }
  }
}

// ---------- GEMM: t[r][:] = (x[r][:] @ W) * ns[r]  (fallback path only) ------
__global__ __launch_bounds__(256) void gemm_ns(const void* __restrict__ xp,
                                               const ushort* __restrict__ wf,
                                               const float* __restrict__ ns,
                                               ushort* __restrict__ t,
                                               const int* __restrict__ flagp,
                                               int forced_bf, int n) {
  __shared__ __align__(16) ushort Ws[16384];
  const int tid = threadIdx.x;
  const int rowbase = blockIdx.x * 64;
  const int eff_bf = forced_bf | *flagp;

#pragma unroll
  for (int i = 0; i < 8; ++i)
    ((uint4*)Ws)[i * 256 + tid] = ((const uint4*)wf)[i * 256 + tid];

  const int w = tid >> 6;
  const int lane = tid & 63;
  const int m = lane & 15;
  const int quad = lane >> 4;

  const int gr_a = rowbase + w * 16 + m;
  const int row_ld = (gr_a < n) ? gr_a : (n - 1);
  bf16x8 a[4];
  if (eff_bf) {
    const ushort* xr = (const ushort*)xp + (size_t)row_ld * 128 + quad * 8;
#pragma unroll
    for (int kk = 0; kk < 4; ++kk)
      a[kk] = *(const bf16x8*)(xr + kk * 32);
  } else {
    const float* xr = (const float*)xp + (size_t)row_ld * 128 + quad * 8;
#pragma unroll
    for (int kk = 0; kk < 4; ++kk) {
      float4 f0 = *(const float4*)(xr + kk * 32);
      float4 f1 = *(const float4*)(xr + kk * 32 + 4);
      uint4 v;
      v.x = pack2(f0.x, f0.y); v.y = pack2(f0.z, f0.w);
      v.z = pack2(f1.x, f1.y); v.w = pack2(f1.z, f1.w);
      a[kk] = __builtin_bit_cast(bf16x8, v);
    }
  }

  int grs[4];
  float nsv[4];
#pragma unroll
  for (int reg = 0; reg < 4; ++reg) {
    int gr = rowbase + w * 16 + quad * 4 + reg;
    grs[reg] = gr;
    nsv[reg] = (gr < n) ? ns[gr] : 0.f;
  }

  __syncthreads();   // Ws ready

#pragma unroll
  for (int c = 0; c < 8; ++c) {
    f32x4 acc = {0.f, 0.f, 0.f, 0.f};
#pragma unroll
    for (int kk = 0; kk < 4; ++kk) {
      bf16x8 b = *(const bf16x8*)&Ws[(((c * 4 + kk) * 4 + quad) * 16 + m) * 8];
      acc = __builtin_amdgcn_mfma_f32_16x16x32_bf16(a[kk], b, acc, 0, 0, 0);
    }
    int col = c * 16 + m;
#pragma unroll
    for (int reg = 0; reg < 4; ++reg) {
      if (grs[reg] < n)
        t[(size_t)grs[reg] * 128 + col] = f2bf(acc[reg] * nsv[reg]);
    }
  }
}

// ---------- shared gather macros (agg structure at the fabric ceiling) -------
// csr indices off the vmcnt counter (one coalesced load / 64 edges + readlane
// broadcast), 16-deep double-buffered gathers, cndmask tails.
#define AGG_ISSUE(buf, gg)                                                    \
  {                                                                           \
    int jb = (gg) << 4;                                                       \
    _Pragma("unroll")                                                         \
    for (int k = 0; k < 16; ++k) {                                            \
      int lj = jb + k;                                                        \
      int sl = (lj < cnt) ? lj : 0;                                           \
      int row = __builtin_amdgcn_readlane(idxv, sl);                          \
      buf[k] = tu[(size_t)row * 64 + lane];                                   \
    }                                                                         \
  }
#define AGG_CONSUME(buf, gg)                                                  \
  {                                                                           \
    int jb = (gg) << 4;                                                       \
    _Pragma("unroll")                                                         \
    for (int k = 0; k < 16; ++k) {                                            \
      uint v = (jb + k < cnt) ? buf[k] : 0u;                                  \
      a0 += __uint_as_float(v << 16);                                         \
      a1 += __uint_as_float(v & 0xffff0000u);                                 \
    }                                                                         \
  }
#define AGG_NODE_BODY()                                                       \
  for (int base_ = 0; base_ < deg; base_ += 64) {                             \
    int cnt = deg - base_;                                                    \
    if (cnt > 64) cnt = 64;                                                   \
    int idxv = 0;                                                             \
    if (lane < cnt) idxv = csr[e0 + base_ + lane];                            \
    int ng = (cnt + 15) >> 4;                                                 \
    uint va[16], vb[16];                                                      \
    AGG_ISSUE(va, 0);                                                         \
    int g = 0;                                                                \
    for (;;) {                                                                \
      if (g + 1 < ng) AGG_ISSUE(vb, g + 1);                                   \
      AGG_CONSUME(va, g);                                                     \
      if (g + 1 >= ng) break;                                                 \
      if (g + 2 < ng) AGG_ISSUE(va, g + 2);                                   \
      AGG_CONSUME(vb, g + 1);                                                 \
      if (g + 2 >= ng) break;                                                 \
      g += 2;                                                                 \
    }                                                                         \
  }

// ---------- fused layer-1 aggregation + layer-2 GEMM (barrier-free) ----------
// Round-7: each WAVE owns 16 nodes end-to-end — aggregates them serially into
// its private LDS Y-tile, then runs its own 32-MFMA 16x128 @ 128x128 pass
// (MFMA is per-wave; no cross-wave coupling exists in the math). No
// __syncthreads at all: removes the round-6 block-barrier imbalance (each
// block waited on its slowest wave, ~1.25x mean) and lets each wave's MFMA
// tail overlap other waves' gathers. W2 B-fragments read directly from
// L2-resident wf (round-6 lesson: LDS-staging W capped occupancy).
__global__ __launch_bounds__(256) void aggemm_k(
    const uint* __restrict__ tu, const int* __restrict__ row_off,
    const int* __restrict__ csr, const float* __restrict__ nd,
    const void* __restrict__ bp, const ushort* __restrict__ wf,
    const float* __restrict__ ns, ushort* __restrict__ t2,
    const int* __restrict__ flagp, int n) {
  __shared__ __align__(16) ushort Y[4][16][136];   // per-wave 4.3 KB tiles
  const int tid = threadIdx.x;
  const int w = tid >> 6;
  const int lane = tid & 63;
  const int nb = blockIdx.x * 64 + w * 16;   // this wave's first node
  const int bf = *flagp;

  float bias0, bias1;
  if (bf) {
    uint bv = ((const uint*)bp)[lane];
    bias0 = bf2f(bv & 0xffffu);
    bias1 = bf2f(bv >> 16);
  } else {
    const float* b32 = (const float*)bp;
    bias0 = b32[2 * lane];
    bias1 = b32[2 * lane + 1];
  }

  // ---- phase 1: this wave aggregates its 16 nodes ----
  for (int i = 0; i < 16; ++i) {
    int node = nb + i;
    float a0 = 0.f, a1 = 0.f;
    if (node < n) {
      int e0 = row_off[node], e1 = row_off[node + 1];
      int deg = e1 - e0;
      AGG_NODE_BODY();
      float nrm = nd[node];
      a0 = fmaxf(a0 * nrm + bias0, 0.f);   // relu (layer-1 output)
      a1 = fmaxf(a1 * nrm + bias1, 0.f);
    }
    *(uint*)&Y[w][i][lane * 2] = pack2(a0, a1);
  }
  // no barrier: Y[w] is wave-private; same-wave LDS RAW ordered by lgkmcnt

  // ---- phase 2: Y(16x128) @ W2 -> t2 (x ns after, as in split path) ----
  const int m = lane & 15;
  const int quad = lane >> 4;
  bf16x8 a[4];
#pragma unroll
  for (int kk = 0; kk < 4; ++kk)
    a[kk] = *(const bf16x8*)&Y[w][m][kk * 32 + quad * 8];

  int grs[4];
  float nsv[4];
#pragma unroll
  for (int reg = 0; reg < 4; ++reg) {
    int gr = nb + quad * 4 + reg;
    grs[reg] = gr;
    nsv[reg] = (gr < n) ? ns[gr] : 0.f;
  }

#pragma unroll
  for (int c = 0; c < 8; ++c) {
    bf16x8 bfr[4];
#pragma unroll
    for (int kk = 0; kk < 4; ++kk)
      bfr[kk] = *(const bf16x8*)&wf[(((c * 4 + kk) * 4 + quad) * 16 + m) * 8];
    f32x4 acc = {0.f, 0.f, 0.f, 0.f};
#pragma unroll
    for (int kk = 0; kk < 4; ++kk)
      acc = __builtin_amdgcn_mfma_f32_16x16x32_bf16(a[kk], bfr[kk], acc, 0, 0, 0);
    int col = c * 16 + m;
#pragma unroll
    for (int reg = 0; reg < 4; ++reg) {
      if (grs[reg] < n)
        t2[(size_t)grs[reg] * 128 + col] = f2bf(acc[reg] * nsv[reg]);
    }
  }
}

// ---------- plain aggregation (final layer / fallback) ----------
__global__ __launch_bounds__(256) void agg_k(const uint* __restrict__ tu,
                                             const int* __restrict__ row_off,
                                             const int* __restrict__ csr,
                                             const float* __restrict__ nd,
                                             const void* __restrict__ bp,
                                             void* __restrict__ outp,
                                             int relu, int is_final,
                                             const int* __restrict__ flagp, int n) {
  int node = (blockIdx.x * 256 + threadIdx.x) >> 6;  // one wave per node
  int lane = threadIdx.x & 63;
  int bf = *flagp;
  if (node >= n) return;
  int e0 = row_off[node], e1 = row_off[node + 1];
  int deg = e1 - e0;
  float a0 = 0.f, a1 = 0.f;
  AGG_NODE_BODY();

  float bias0, bias1;
  if (bf) {
    uint bv = ((const uint*)bp)[lane];
    bias0 = bf2f(bv & 0xffffu);
    bias1 = bf2f(bv >> 16);
  } else {
    const float* b32 = (const float*)bp;
    bias0 = b32[2 * lane];
    bias1 = b32[2 * lane + 1];
  }
  float nrm = nd[node];
  float o0 = a0 * nrm + bias0;
  float o1 = a1 * nrm + bias1;
  if (relu) { o0 = fmaxf(o0, 0.f); o1 = fmaxf(o1, 0.f); }
  if (!is_final || bf) {
    ((uint*)outp)[(size_t)node * 64 + lane] = pack2(o0, o1);
  } else {
    ((float2*)outp)[(size_t)node * 64 + lane] = make_float2(o0, o1);
  }
}

extern "C" void kernel_launch(void* const* d_in, const int* in_sizes, int n_in,
                              void* d_out, int out_size, void* d_ws, size_t ws_size,
                              hipStream_t stream) {
  int n = in_sizes[0] / 128;   // 100000 nodes
  int E = in_sizes[1];         // 1600000 edges

  const void* feat = d_in[0];
  const int* src = (const int*)d_in[1];
  const int* dst = (const int*)d_in[2];
  const void* W1 = d_in[3];
  const void* b1 = d_in[4];
  const void* W2 = d_in[5];
  const void* b2 = d_in[6];

  // sort geometry
  const int B = (n + 511) >> 9;              // coarse buckets (196 for n=100k)
  const int P = (E + 4095) >> 12;            // edge blocks of 4096
  int cap = ((2 * (E / B)) + 63) & ~63;      // padded bucket capacity (2x mean)
  if (cap < 1024) cap = 1024;

  // workspace carve-up (256B-aligned slabs)
  char* p = (char*)d_ws;
  auto alloc = [&](size_t bytes) -> char* {
    char* q = p;
    p += (bytes + 255) & ~(size_t)255;
    return q;
  };
  int* flag = (int*)alloc(256);
  // region A: t (25.6 MB, live from fine_k's fused gemm on) aliases sort
  // scratch (dead by then): ebuf_d (B*cap*4) + ebuf_s (B*cap*2) + cursors
  ushort* t = (ushort*)alloc((size_t)n * 128 * 2);
  uint* ebuf_d = (uint*)t;                                   // B*cap*4
  ushort* ebuf_s = (ushort*)(ebuf_d + (size_t)B * cap);      // B*cap*2
  int* gcur_d = (int*)(ebuf_s + (size_t)B * cap);            // B
  int* gcur_s = gcur_d + B;                                  // B
  // persistent slabs
  ushort* wf1 = (ushort*)alloc(16384 * 2);
  ushort* wf2 = (ushort*)alloc(16384 * 2);
  float* ns = (float*)alloc((size_t)n * 4);
  float* nd = (float*)alloc((size_t)n * 4);
  int* row_off = (int*)alloc((size_t)(n + 1) * 4);
  int* csr = (int*)alloc((size_t)E * 4);
  // t2 for the fused path (layer-2 messages); fallback uses d_out as y1
  ushort* t2 = (ushort*)alloc((size_t)n * 128 * 2);
  const bool fused = ((size_t)(p - (char*)d_ws) <= ws_size);

  const int TB = 256;
  const int gGemm = (n + 63) / 64;
  const int gAgg = (n + 3) / 4;
  const int gFus = (n + 63) / 64;   // 64 nodes per block (16 per wave)

  // WAIT: fine_k's fused gemm writes t, which ALIASES ebuf while fine_k is
  // still reading ebuf. NOT safe... except: src block b's gemm writes
  // t rows [b*512, b*512+512) = bytes [b*131072*... no — overlap is real.
  // Keep gemm in fine_k but write to t2's slab instead, and swap roles:
  // t2 <- layer-1 messages (non-aliased), t <- layer-2 messages.
  ushort* tL1 = t2;   // layer-1 messages (separate slab, no aliasing)
  ushort* tL2 = t;    // layer-2 messages (sort scratch dead by aggemm time)

  hipMemsetAsync(gcur_d, 0, 2 * (size_t)B * 4, stream);
  ecat_k<<<P + 16, TB, 0, stream>>>(src, dst, ebuf_d, ebuf_s, gcur_d, gcur_s,
                                    B, cap, E, P, W1, W2, wf1, wf2,
                                    (const uint*)feat, flag);
  fine_k<<<2 * B, TB, 0, stream>>>(ebuf_d, ebuf_s, gcur_d, gcur_s,
                                   row_off, csr, ns, nd,
                                   feat, wf1, tL1, flag, B, cap, n, E);

  if (fused) {
    // layer-1 aggregation fused with layer-2 GEMM (no y1 round trip)
    aggemm_k<<<gFus, TB, 0, stream>>>((const uint*)tL1, row_off, csr, nd, b1,
                                      wf2, ns, tL2, flag, n);
    agg_k<<<gAgg, TB, 0, stream>>>((const uint*)tL2, row_off, csr, nd, b2,
                                   d_out, 0, 1, flag, n);
  } else {
    // fallback: split path (y1 lives in d_out, overwritten by final)
    ushort* y1 = (ushort*)d_out;
    agg_k<<<gAgg, TB, 0, stream>>>((const uint*)tL1, row_off, csr, nd, b1,
                                   (void*)y1, 1, 0, flag, n);
    gemm_ns<<<gGemm, TB, 0, stream>>>((const void*)y1, wf2, ns, tL2, flag, 1, n);
    agg_k<<<gAgg, TB, 0, stream>>>((const uint*)tL2, row_off, csr, nd, b2,
                                   d_out, 0, 1, flag, n);
  }
}

// Round 8
// 317.847 us; speedup vs baseline: 1.0960x; 1.0960x over previous
//
#include <hip/hip_runtime.h>

typedef unsigned int uint;
typedef unsigned short ushort;

typedef float f32x4 __attribute__((ext_vector_type(4)));
typedef __bf16 bf16x8 __attribute__((ext_vector_type(8)));

__device__ __forceinline__ float bf2f(uint bits) {
  return __uint_as_float(bits << 16);
}
__device__ __forceinline__ ushort f2bf(float f) {
  uint u = __float_as_uint(f);
  u += 0x7fffu + ((u >> 16) & 1u);   // round-to-nearest-even
  return (ushort)(u >> 16);
}
__device__ __forceinline__ uint pack2(float a, float b) {
  return (uint)f2bf(a) | ((uint)f2bf(b) << 16);
}

// inclusive block scan of per-thread values over 256 threads (ts = 256-slot LDS)
__device__ __forceinline__ void block_scan256(int v, int* ts, int tid) {
  ts[tid] = v;
  __syncthreads();
  for (int off = 1; off < 256; off <<= 1) {
    int t_ = 0;
    if (tid >= off) t_ = ts[tid - off];
    __syncthreads();
    if (tid >= off) ts[tid] += t_;
    __syncthreads();
  }
}

// ================= one-pass bucket scatter (single edge read) ================
// Coarse bucket = 512-node range (B = ceil(n/512); B <= 256 for n <= 131072).
// Each block stages 4096 edges in LDS, histograms them, RESERVES a per-bucket
// range via one global atomicAdd per (block,bucket) into capacity-padded
// bucket regions (cap = 2x mean; overflow prob for uniform edges ~ e^-2700),
// then scatters from LDS. Bucket order is arbitrary -> fine_k's counting sort
// and the sum-aggregation are order-independent.
// Blocks [P, P+16) piggyback the W pre-swizzle + dtype probe (saves a launch).
__global__ __launch_bounds__(256) void ecat_k(
    const int* __restrict__ src, const int* __restrict__ dst,
    uint* __restrict__ ebuf_d, ushort* __restrict__ ebuf_s,
    int* __restrict__ gcur_d, int* __restrict__ gcur_s,
    int B, int cap, int E, int P,
    const void* __restrict__ W1p, const void* __restrict__ W2p,
    ushort* __restrict__ wf1, ushort* __restrict__ wf2,
    const uint* __restrict__ xu, int* __restrict__ flagp) {
  __shared__ int s_s[4096], s_d[4096];   // 32 KB edge stage
  __shared__ int hd[1024], hs[1024];     // 8 KB hist -> cursors
  __shared__ int bfs;
  const int tid = threadIdx.x;

  if (blockIdx.x >= P) {   // ---- wswz role (16 blocks) ----
    if (tid < 64) {        // wave 0: bf16-vs-f32 probe on first 64 feat words
      uint u = xu[tid];
      uint e = (u >> 7) & 0xFFu;
      unsigned long long mm = __ballot(e >= 116u && e <= 130u);
      if (tid == 0) {
        int f = (__builtin_popcountll(mm) >= 32) ? 1 : 0;
        bfs = f;
        if (blockIdx.x == P) flagp[0] = f;
      }
    }
    __syncthreads();
    const int bf = bfs;
    int vid = (blockIdx.x - P) * 256 + tid;   // 0..4095
    const void* W = (vid & 2048) ? W2p : W1p;
    ushort* wf = (vid & 2048) ? wf2 : wf1;
    int chunk = vid & 2047;
    int n0 = chunk & 15;
    int quad = (chunk >> 4) & 3;
    int kk = (chunk >> 6) & 3;
    int c = chunk >> 8;
    int col = c * 16 + n0;
#pragma unroll
    for (int j = 0; j < 8; ++j) {
      int idx = (kk * 32 + quad * 8 + j) * 128 + col;
      ushort v = bf ? ((const ushort*)W)[idx] : f2bf(((const float*)W)[idx]);
      wf[chunk * 8 + j] = v;
    }
    return;
  }

  // ---- edge-scatter role ----
  const int blk = blockIdx.x;
  for (int i = tid; i < B; i += 256) { hd[i] = 0; hs[i] = 0; }
  int e0 = blk << 12;
  int cnt = E - e0;
  if (cnt > 4096) cnt = 4096;
  __syncthreads();
  for (int j = tid; j < cnt; j += 256) {
    int s = src[e0 + j], d = dst[e0 + j];
    s_s[j] = s;
    s_d[j] = d;
    atomicAdd(&hd[d >> 9], 1);
    atomicAdd(&hs[s >> 9], 1);
  }
  __syncthreads();
  for (int i = tid; i < B; i += 256) {   // reserve ranges (global atomics)
    int c = hd[i];
    if (c) hd[i] = i * cap + atomicAdd(&gcur_d[i], c);
    int c2 = hs[i];
    if (c2) hs[i] = i * cap + atomicAdd(&gcur_s[i], c2);
  }
  __syncthreads();
  for (int j = tid; j < cnt; j += 256) {
    int s = s_s[j], d = s_d[j];
    int pd = atomicAdd(&hd[d >> 9], 1);
    ebuf_d[pd] = (uint)s | ((uint)(d & 511) << 17);   // src(17b)|dstlocal(9b)
    int ps = atomicAdd(&hs[s >> 9], 1);
    ebuf_s[ps] = (ushort)(s & 511);
  }
}

// K5: per-bucket fine pass. Dense base recovered by an in-block reduce over
// the final global cursor counts (B <= 256 values). dst side: 512-bin LDS
// histogram + scan -> row_off/nd/csr. src side: histogram -> ns.
__global__ __launch_bounds__(256) void fine_k(
    const uint* __restrict__ ebuf_d, const ushort* __restrict__ ebuf_s,
    const int* __restrict__ gcur_d, const int* __restrict__ gcur_s,
    int* __restrict__ row_off, int* __restrict__ csr,
    float* __restrict__ ns, float* __restrict__ nd,
    int B, int cap, int n, int E) {
  __shared__ int cnt[512];
  __shared__ int off[512];
  __shared__ int ts[256];
  const int tid = threadIdx.x;
  const int id = blockIdx.x;          // [0,2B)
  for (int i = tid; i < 512; i += 256) cnt[i] = 0;

  const int b = (id < B) ? id : id - B;
  const int* cur = (id < B) ? gcur_d : gcur_s;
  // dense base lo = sum_{i<b} cur[i]; bucket count cb = cur[b]
  int part = 0;
#pragma unroll
  for (int k = 0; k < 4; ++k) {
    int i = tid * 4 + k;
    if (i < b) part += cur[i];
  }
  block_scan256(part, ts, tid);   // barriers also publish the cnt[] zero-init
  int lo = ts[255];
  int cb = cur[b];
  const int rb = b * cap;          // padded read base
  __syncthreads();                 // ts reused below

  if (id < B) {
    for (int e = tid; e < cb; e += 256)
      atomicAdd(&cnt[(ebuf_d[rb + e] >> 17) & 511], 1);
    __syncthreads();
    int c0 = cnt[2 * tid], c1 = cnt[2 * tid + 1];
    block_scan256(c0 + c1, ts, tid);
    int excl = (tid > 0) ? ts[tid - 1] : 0;
    off[2 * tid] = excl;
    off[2 * tid + 1] = excl + c0;
    __syncthreads();
    for (int i = tid; i < 512; i += 256) {
      int g = b * 512 + i;
      if (g < n) {
        row_off[g] = lo + off[i];
        nd[g] = rsqrtf(fmaxf((float)cnt[i], 1.f));
      }
    }
    if (id == 0 && tid == 0) row_off[n] = E;
    __syncthreads();
    for (int i = tid; i < 512; i += 256) cnt[i] = off[i];  // cnt -> cursor
    __syncthreads();
    for (int e = tid; e < cb; e += 256) {
      uint v = ebuf_d[rb + e];
      int l = (v >> 17) & 511;
      int slot = atomicAdd(&cnt[l], 1);
      csr[lo + slot] = (int)(v & 0x1FFFFu);   // L2 write-combines to full lines
    }
  } else {
    for (int e = tid; e < cb; e += 256)
      atomicAdd(&cnt[ebuf_s[rb + e]], 1);
    __syncthreads();
    for (int i = tid; i < 512; i += 256) {
      int g = b * 512 + i;
      if (g < n) ns[g] = rsqrtf(fmaxf((float)cnt[i], 1.f));
    }
  }
}

// ---------- GEMM: t[r][:] = (x[r][:] @ W) * ns[r] ----------
// A-fragments load directly from global (16 full 64B lines per load instr);
// only W is LDS-staged (32 KB).
__global__ __launch_bounds__(256) void gemm_ns(const void* __restrict__ xp,
                                               const ushort* __restrict__ wf,
                                               const float* __restrict__ ns,
                                               ushort* __restrict__ t,
                                               const int* __restrict__ flagp,
                                               int forced_bf, int n) {
  __shared__ __align__(16) ushort Ws[16384];
  const int tid = threadIdx.x;
  const int rowbase = blockIdx.x * 64;
  const int eff_bf = forced_bf | *flagp;

#pragma unroll
  for (int i = 0; i < 8; ++i)
    ((uint4*)Ws)[i * 256 + tid] = ((const uint4*)wf)[i * 256 + tid];

  const int w = tid >> 6;
  const int lane = tid & 63;
  const int m = lane & 15;
  const int quad = lane >> 4;

  const int gr_a = rowbase + w * 16 + m;            // row this lane loads A from
  const int row_ld = (gr_a < n) ? gr_a : (n - 1);   // clamp: no OOB fault;
                                                    // garbage rows never stored
  bf16x8 a[4];
  if (eff_bf) {
    const ushort* xr = (const ushort*)xp + (size_t)row_ld * 128 + quad * 8;
#pragma unroll
    for (int kk = 0; kk < 4; ++kk)
      a[kk] = *(const bf16x8*)(xr + kk * 32);
  } else {
    const float* xr = (const float*)xp + (size_t)row_ld * 128 + quad * 8;
#pragma unroll
    for (int kk = 0; kk < 4; ++kk) {
      float4 f0 = *(const float4*)(xr + kk * 32);
      float4 f1 = *(const float4*)(xr + kk * 32 + 4);
      uint4 v;
      v.x = pack2(f0.x, f0.y); v.y = pack2(f0.z, f0.w);
      v.z = pack2(f1.x, f1.y); v.w = pack2(f1.z, f1.w);
      a[kk] = __builtin_bit_cast(bf16x8, v);
    }
  }

  int grs[4];
  float nsv[4];
#pragma unroll
  for (int reg = 0; reg < 4; ++reg) {
    int gr = rowbase + w * 16 + quad * 4 + reg;
    grs[reg] = gr;
    nsv[reg] = (gr < n) ? ns[gr] : 0.f;
  }

  __syncthreads();   // Ws ready

#pragma unroll
  for (int c = 0; c < 8; ++c) {
    f32x4 acc = {0.f, 0.f, 0.f, 0.f};
#pragma unroll
    for (int kk = 0; kk < 4; ++kk) {
      bf16x8 b = *(const bf16x8*)&Ws[(((c * 4 + kk) * 4 + quad) * 16 + m) * 8];
      acc = __builtin_amdgcn_mfma_f32_16x16x32_bf16(a[kk], b, acc, 0, 0, 0);
    }
    int col = c * 16 + m;
#pragma unroll
    for (int reg = 0; reg < 4; ++reg) {
      if (grs[reg] < n)
        t[(size_t)grs[reg] * 128 + col] = f2bf(acc[reg] * nsv[reg]);
    }
  }
}

// ---------- shared gather macros (agg structure at the fabric ceiling) -------
// csr indices off the vmcnt counter (one coalesced load / 64 edges + readlane
// broadcast), 16-deep double-buffered gathers, cndmask tails.
#define AGG_ISSUE(buf, gg)                                                    \
  {                                                                           \
    int jb = (gg) << 4;                                                       \
    _Pragma("unroll")                                                         \
    for (int k = 0; k < 16; ++k) {                                            \
      int lj = jb + k;                                                        \
      int sl = (lj < cnt) ? lj : 0;                                           \
      int row = __builtin_amdgcn_readlane(idxv, sl);                          \
      buf[k] = tu[(size_t)row * 64 + lane];                                   \
    }                                                                         \
  }
#define AGG_CONSUME(buf, gg)                                                  \
  {                                                                           \
    int jb = (gg) << 4;                                                       \
    _Pragma("unroll")                                                         \
    for (int k = 0; k < 16; ++k) {                                            \
      uint v = (jb + k < cnt) ? buf[k] : 0u;                                  \
      a0 += __uint_as_float(v << 16);                                         \
      a1 += __uint_as_float(v & 0xffff0000u);                                 \
    }                                                                         \
  }
#define AGG_NODE_BODY()                                                       \
  for (int base_ = 0; base_ < deg; base_ += 64) {                             \
    int cnt = deg - base_;                                                    \
    if (cnt > 64) cnt = 64;                                                   \
    int idxv = 0;                                                             \
    if (lane < cnt) idxv = csr[e0 + base_ + lane];                            \
    int ng = (cnt + 15) >> 4;                                                 \
    uint va[16], vb[16];                                                      \
    AGG_ISSUE(va, 0);                                                         \
    int g = 0;                                                                \
    for (;;) {                                                                \
      if (g + 1 < ng) AGG_ISSUE(vb, g + 1);                                   \
      AGG_CONSUME(va, g);                                                     \
      if (g + 1 >= ng) break;                                                 \
      if (g + 2 < ng) AGG_ISSUE(va, g + 2);                                   \
      AGG_CONSUME(vb, g + 1);                                                 \
      if (g + 2 >= ng) break;                                                 \
      g += 2;                                                                 \
    }                                                                         \
  }

// ---------- fused layer-1 aggregation + layer-2 GEMM ----------
// Round-6 structure (best measured): block = 4 waves = 16 nodes, 4 nodes per
// wave, one barrier, then the 4 waves split the 16x128 @ 128x128 MFMA pass.
// NO Ws LDS stage (round-5 lesson: 32 KB LDS capped occupancy at 39% for the
// long gather phase); B-fragments read directly from L2-resident wf.
// Round-7 lesson: barrier-free wave-owns-16-rows cuts chip-wide wave count 4x
// (6250 vs 25000) -> occupancy 37%, gathers starve at 1.98 TB/s. The barrier
// imbalance (~1.25x mean on the slowest of 4 waves) is the cheaper evil.
__global__ __launch_bounds__(256) void aggemm_k(
    const uint* __restrict__ tu, const int* __restrict__ row_off,
    const int* __restrict__ csr, const float* __restrict__ nd,
    const void* __restrict__ bp, const ushort* __restrict__ wf,
    const float* __restrict__ ns, ushort* __restrict__ t2,
    const int* __restrict__ flagp, int n) {
  __shared__ __align__(16) ushort Y[16][136];   // +8 pad: 2-way (free) banks
  const int tid = threadIdx.x;
  const int w = tid >> 6;
  const int lane = tid & 63;
  const int nb = blockIdx.x * 16;
  const int bf = *flagp;

  float bias0, bias1;
  if (bf) {
    uint bv = ((const uint*)bp)[lane];
    bias0 = bf2f(bv & 0xffffu);
    bias1 = bf2f(bv >> 16);
  } else {
    const float* b32 = (const float*)bp;
    bias0 = b32[2 * lane];
    bias1 = b32[2 * lane + 1];
  }

  // ---- phase 1: aggregate 4 nodes per wave ----
  for (int i = 0; i < 4; ++i) {
    int r = w * 4 + i;
    int node = nb + r;
    float a0 = 0.f, a1 = 0.f;
    if (node < n) {
      int e0 = row_off[node], e1 = row_off[node + 1];
      int deg = e1 - e0;
      AGG_NODE_BODY();
      float nrm = nd[node];
      a0 = fmaxf(a0 * nrm + bias0, 0.f);   // relu (layer-1 output)
      a1 = fmaxf(a1 * nrm + bias1, 0.f);
    }
    *(uint*)&Y[r][lane * 2] = pack2(a0, a1);
  }
  __syncthreads();

  // ---- phase 2: Y(16x128) @ W2 -> t2 (x ns after, as in split path) ----
  const int m = lane & 15;
  const int quad = lane >> 4;
  bf16x8 a[4];
#pragma unroll
  for (int kk = 0; kk < 4; ++kk)
    a[kk] = *(const bf16x8*)&Y[m][kk * 32 + quad * 8];

  int grs[4];
  float nsv[4];
#pragma unroll
  for (int reg = 0; reg < 4; ++reg) {
    int gr = nb + quad * 4 + reg;
    grs[reg] = gr;
    nsv[reg] = (gr < n) ? ns[gr] : 0.f;
  }

#pragma unroll
  for (int cc = 0; cc < 2; ++cc) {
    int c = w * 2 + cc;
    bf16x8 bfr[4];
#pragma unroll
    for (int kk = 0; kk < 4; ++kk)
      bfr[kk] = *(const bf16x8*)&wf[(((c * 4 + kk) * 4 + quad) * 16 + m) * 8];
    f32x4 acc = {0.f, 0.f, 0.f, 0.f};
#pragma unroll
    for (int kk = 0; kk < 4; ++kk)
      acc = __builtin_amdgcn_mfma_f32_16x16x32_bf16(a[kk], bfr[kk], acc, 0, 0, 0);
    int col = c * 16 + m;
#pragma unroll
    for (int reg = 0; reg < 4; ++reg) {
      if (grs[reg] < n)
        t2[(size_t)grs[reg] * 128 + col] = f2bf(acc[reg] * nsv[reg]);
    }
  }
}

// ---------- plain aggregation (final layer / fallback) ----------
__global__ __launch_bounds__(256) void agg_k(const uint* __restrict__ tu,
                                             const int* __restrict__ row_off,
                                             const int* __restrict__ csr,
                                             const float* __restrict__ nd,
                                             const void* __restrict__ bp,
                                             void* __restrict__ outp,
                                             int relu, int is_final,
                                             const int* __restrict__ flagp, int n) {
  int node = (blockIdx.x * 256 + threadIdx.x) >> 6;  // one wave per node
  int lane = threadIdx.x & 63;
  int bf = *flagp;
  if (node >= n) return;
  int e0 = row_off[node], e1 = row_off[node + 1];
  int deg = e1 - e0;
  float a0 = 0.f, a1 = 0.f;
  AGG_NODE_BODY();

  float bias0, bias1;
  if (bf) {
    uint bv = ((const uint*)bp)[lane];
    bias0 = bf2f(bv & 0xffffu);
    bias1 = bf2f(bv >> 16);
  } else {
    const float* b32 = (const float*)bp;
    bias0 = b32[2 * lane];
    bias1 = b32[2 * lane + 1];
  }
  float nrm = nd[node];
  float o0 = a0 * nrm + bias0;
  float o1 = a1 * nrm + bias1;
  if (relu) { o0 = fmaxf(o0, 0.f); o1 = fmaxf(o1, 0.f); }
  if (!is_final || bf) {
    ((uint*)outp)[(size_t)node * 64 + lane] = pack2(o0, o1);
  } else {
    ((float2*)outp)[(size_t)node * 64 + lane] = make_float2(o0, o1);
  }
}

extern "C" void kernel_launch(void* const* d_in, const int* in_sizes, int n_in,
                              void* d_out, int out_size, void* d_ws, size_t ws_size,
                              hipStream_t stream) {
  int n = in_sizes[0] / 128;   // 100000 nodes
  int E = in_sizes[1];         // 1600000 edges

  const void* feat = d_in[0];
  const int* src = (const int*)d_in[1];
  const int* dst = (const int*)d_in[2];
  const void* W1 = d_in[3];
  const void* b1 = d_in[4];
  const void* W2 = d_in[5];
  const void* b2 = d_in[6];

  // sort geometry
  const int B = (n + 511) >> 9;              // coarse buckets (196 for n=100k)
  const int P = (E + 4095) >> 12;            // edge blocks of 4096
  int cap = ((2 * (E / B)) + 63) & ~63;      // padded bucket capacity (2x mean)
  if (cap < 1024) cap = 1024;

  // workspace carve-up (256B-aligned slabs)
  char* p = (char*)d_ws;
  auto alloc = [&](size_t bytes) -> char* {
    char* q = p;
    p += (bytes + 255) & ~(size_t)255;
    return q;
  };
  int* flag = (int*)alloc(256);
  // region A: t (25.6 MB, live from gemm1 on) aliases sort scratch (dead by
  // then): ebuf_d (B*cap*4) + ebuf_s (B*cap*2) + cursors
  ushort* t = (ushort*)alloc((size_t)n * 128 * 2);
  uint* ebuf_d = (uint*)t;                                   // B*cap*4
  ushort* ebuf_s = (ushort*)(ebuf_d + (size_t)B * cap);      // B*cap*2
  int* gcur_d = (int*)(ebuf_s + (size_t)B * cap);            // B
  int* gcur_s = gcur_d + B;                                  // B
  // persistent slabs
  ushort* wf1 = (ushort*)alloc(16384 * 2);
  ushort* wf2 = (ushort*)alloc(16384 * 2);
  float* ns = (float*)alloc((size_t)n * 4);
  float* nd = (float*)alloc((size_t)n * 4);
  int* row_off = (int*)alloc((size_t)(n + 1) * 4);
  int* csr = (int*)alloc((size_t)E * 4);
  // t2 for the fused path (layer-2 messages); fallback uses d_out as y1
  ushort* t2 = (ushort*)alloc((size_t)n * 128 * 2);
  const bool fused = ((size_t)(p - (char*)d_ws) <= ws_size);

  const int TB = 256;
  const int gGemm = (n + 63) / 64;
  const int gAgg = (n + 3) / 4;
  const int gFus = (n + 15) / 16;

  hipMemsetAsync(gcur_d, 0, 2 * (size_t)B * 4, stream);
  ecat_k<<<P + 16, TB, 0, stream>>>(src, dst, ebuf_d, ebuf_s, gcur_d, gcur_s,
                                    B, cap, E, P, W1, W2, wf1, wf2,
                                    (const uint*)feat, flag);
  fine_k<<<2 * B, TB, 0, stream>>>(ebuf_d, ebuf_s, gcur_d, gcur_s,
                                   row_off, csr, ns, nd, B, cap, n, E);

  // layer 1 GEMM
  gemm_ns<<<gGemm, TB, 0, stream>>>(feat, wf1, ns, t, flag, 0, n);

  if (fused) {
    // layer-1 aggregation fused with layer-2 GEMM (no y1 round trip)
    aggemm_k<<<gFus, TB, 0, stream>>>((const uint*)t, row_off, csr, nd, b1,
                                      wf2, ns, t2, flag, n);
    agg_k<<<gAgg, TB, 0, stream>>>((const uint*)t2, row_off, csr, nd, b2,
                                   d_out, 0, 1, flag, n);
  } else {
    // fallback: split path (y1 lives in d_out, overwritten by final)
    ushort* y1 = (ushort*)d_out;
    agg_k<<<gAgg, TB, 0, stream>>>((const uint*)t, row_off, csr, nd, b1,
                                   (void*)y1, 1, 0, flag, n);
    gemm_ns<<<gGemm, TB, 0, stream>>>((const void*)y1, wf2, ns, t, flag, 1, n);
    agg_k<<<gAgg, TB, 0, stream>>>((const uint*)t, row_off, csr, nd, b2,
                                   d_out, 0, 1, flag, n);
  }
}